// Round 13
// baseline (2024.300 us; speedup 1.0000x reference)
//
#include <hip/hip_runtime.h>
#include <hip/hip_bf16.h>
#include <cstdint>
#include <cstddef>

#define Dm 1024
#define Sm 512
#define Bm 2
#define Nm 4096
#define Lm 4
#define Vm 32000

typedef __attribute__((ext_vector_type(8))) short short8;
typedef __attribute__((ext_vector_type(4))) float floatx4;

__device__ __forceinline__ unsigned short f2b(float f){
  union { float f; unsigned u; } v; v.f = f;
  unsigned r = (v.u + 0x7fffu + ((v.u >> 16) & 1u)) >> 16;
  return (unsigned short)r;
}

// Exact f32 threshold for the ternary decision (see round-6 proof).
__device__ __forceinline__ float tern_thresh(double s64){
  float T = (float)(s64 * 0.5);
  if ((double)T > s64 * 0.5) T = __uint_as_float(__float_as_uint(T) - 1u);
  return T;
}

// ---------------- fused abs-sum (grid.y = slots) ----------------
struct AbsumArgs { const float* src[10]; long n4[10]; };

__global__ __launch_bounds__(256) void absum_all_kernel(
    AbsumArgs a, double* __restrict__ parts)
{
  int slot = blockIdx.y;
  const float* x = a.src[slot];
  long n4 = a.n4[slot];
  long i = (long)blockIdx.x * blockDim.x + threadIdx.x;
  long stride = (long)gridDim.x * blockDim.x;
  double s = 0.0;
  for (; i < n4; i += stride){
    float4 v = ((const float4*)x)[i];
    s += (double)fabsf(v.x) + (double)fabsf(v.y)
       + (double)fabsf(v.z) + (double)fabsf(v.w);
  }
  #pragma unroll
  for (int off = 32; off; off >>= 1) s += __shfl_down(s, off, 64);
  __shared__ double wsum[4];
  int lane = threadIdx.x & 63, wv = threadIdx.x >> 6;
  if (lane == 0) wsum[wv] = s;
  __syncthreads();
  if (threadIdx.x == 0)
    parts[(size_t)slot * 512 + blockIdx.x] = wsum[0]+wsum[1]+wsum[2]+wsum[3];
}

__global__ __launch_bounds__(256) void absum_final_kernel(
    const double* __restrict__ part, double* __restrict__ scales)
{
  const double* p = part + (size_t)blockIdx.x * 512;
  int tid = threadIdx.x;
  double s = p[tid] + p[tid + 256];
  #pragma unroll
  for (int off = 32; off; off >>= 1) s += __shfl_down(s, off, 64);
  __shared__ double wsum[4];
  int lane = tid & 63, wv = tid >> 6;
  if (lane == 0) wsum[wv] = s;
  __syncthreads();
  if (tid == 0) scales[blockIdx.x] = wsum[0]+wsum[1]+wsum[2]+wsum[3];
}

// ---------------- fused weight pre-pack (grid.y = slots) ----------------
struct PackArgs {
  const float* src[10]; unsigned short* dst[10];
  long n4[10]; int sidx[10]; double cnt[10];
};

__global__ __launch_bounds__(256) void pack_all_kernel(
    PackArgs a, const double* __restrict__ scales)
{
  int slot = blockIdx.y;
  const float* src = a.src[slot];
  unsigned short* dst = a.dst[slot];
  long n4 = a.n4[slot];
  bool tern = (a.sidx[slot] >= 0);
  float T = 0.f;
  if (tern){
    double s64 = scales[a.sidx[slot]] / a.cnt[slot] + 1e-8;
    T = tern_thresh(s64);
  }
  long i = (long)blockIdx.x * blockDim.x + threadIdx.x;
  long stride = (long)gridDim.x * blockDim.x;
  for (; i < n4; i += stride){
    float4 v = ((const float4*)src)[i];
    ushort4 u;
    if (tern){
      u.x = (v.x > T) ? 0x3F80 : ((v.x < -T) ? 0xBF80 : 0);
      u.y = (v.y > T) ? 0x3F80 : ((v.y < -T) ? 0xBF80 : 0);
      u.z = (v.z > T) ? 0x3F80 : ((v.z < -T) ? 0xBF80 : 0);
      u.w = (v.w > T) ? 0x3F80 : ((v.w < -T) ? 0xBF80 : 0);
    } else {
      u.x = f2b(v.x); u.y = f2b(v.y); u.z = f2b(v.z); u.w = f2b(v.w);
    }
    ((ushort4*)dst)[i] = u;
  }
}

// ---------------- ternary embedding + positional ----------------
__global__ __launch_bounds__(256) void embed_kernel(
    const int* __restrict__ ids, const float* __restrict__ emb,
    const float* __restrict__ pos, const double* __restrict__ ssum,
    unsigned short* __restrict__ xb)
{
  int row = blockIdx.x;            // b*512 + s
  int sp  = row & (Sm - 1);
  int id  = ids[row];
  double s64 = ssum[0] / ((double)Vm * (double)Dm) + 1e-8;
  float s = (float)s64;
  float T = tern_thresh(s64);
  int d = threadIdx.x * 4;
  float4 wv = *(const float4*)(emb + (size_t)id * Dm + d);
  float4 pv = *(const float4*)(pos + (size_t)sp * Dm + d);
  float q0 = (wv.x > T) ? 1.f : ((wv.x < -T) ? -1.f : 0.f);
  float q1 = (wv.y > T) ? 1.f : ((wv.y < -T) ? -1.f : 0.f);
  float q2 = (wv.z > T) ? 1.f : ((wv.z < -T) ? -1.f : 0.f);
  float q3 = (wv.w > T) ? 1.f : ((wv.w < -T) ? -1.f : 0.f);
  float y0 = s * q0 + pv.x;
  float y1 = s * q1 + pv.y;
  float y2 = s * q2 + pv.z;
  float y3 = s * q3 + pv.w;
  ushort4 u = make_ushort4(f2b(y0), f2b(y1), f2b(y2), f2b(y3));
  *(ushort4*)(xb + (size_t)row * Dm + d) = u;
}

// ---------------- bf16 MFMA GEMM (128x128 tile) ----------------
// WM = 0: W f32 plain | 1: W f32 ternary | 2: W bf16 pre-packed.
template<int WM>
__global__ __launch_bounds__(256) void gemm_t(
    const unsigned short* __restrict__ A, const void* __restrict__ Wp,
    const float* __restrict__ bias, const double* __restrict__ ssum, double cnt,
    int relu, float* __restrict__ outf, unsigned short* __restrict__ outb,
    int M, int N, int K)
{
  __shared__ unsigned short As[128][40];
  __shared__ unsigned short Bs[128][40];
  int tid = threadIdx.x;
  int wave = tid >> 6, lane = tid & 63;
  int wm = wave >> 1, wn = wave & 1;
  int bm = blockIdx.y, bn = blockIdx.x;

  float s = 1.f, T = 0.f;
  if (ssum){
    double s64 = ssum[0] / cnt + 1e-8;
    s = (float)s64;
    T = tern_thresh(s64);
  }

  int arow = tid >> 1, achunk = tid & 1;
  const unsigned short* Ag = A + (size_t)(bm * 128 + arow) * K + achunk * 16;
  const float* Wg32 = (const float*)Wp + (size_t)(bn * 128 + arow) * K + achunk * 16;
  const unsigned short* Wg16 = (const unsigned short*)Wp + (size_t)(bn * 128 + arow) * K + achunk * 16;

  floatx4 acc[4][4];
  #pragma unroll
  for (int i = 0; i < 4; i++)
    #pragma unroll
    for (int j = 0; j < 4; j++)
      acc[i][j] = (floatx4){0.f, 0.f, 0.f, 0.f};

  for (int k0 = 0; k0 < K; k0 += 32){
    __syncthreads();
    uint4 a0 = *(const uint4*)(Ag + k0);
    uint4 a1 = *(const uint4*)(Ag + k0 + 8);
    *(uint4*)&As[arow][achunk * 16]     = a0;
    *(uint4*)&As[arow][achunk * 16 + 8] = a1;
    if (WM == 2){
      uint4 b0 = *(const uint4*)(Wg16 + k0);
      uint4 b1 = *(const uint4*)(Wg16 + k0 + 8);
      *(uint4*)&Bs[arow][achunk * 16]     = b0;
      *(uint4*)&Bs[arow][achunk * 16 + 8] = b1;
    } else {
      unsigned short tmp[16];
      #pragma unroll
      for (int q = 0; q < 4; q++){
        float4 wv = *(const float4*)(Wg32 + k0 + q * 4);
        if (WM == 1){
          tmp[q*4+0] = (wv.x > T) ? 0x3F80 : ((wv.x < -T) ? 0xBF80 : 0);
          tmp[q*4+1] = (wv.y > T) ? 0x3F80 : ((wv.y < -T) ? 0xBF80 : 0);
          tmp[q*4+2] = (wv.z > T) ? 0x3F80 : ((wv.z < -T) ? 0xBF80 : 0);
          tmp[q*4+3] = (wv.w > T) ? 0x3F80 : ((wv.w < -T) ? 0xBF80 : 0);
        } else {
          tmp[q*4+0] = f2b(wv.x); tmp[q*4+1] = f2b(wv.y);
          tmp[q*4+2] = f2b(wv.z); tmp[q*4+3] = f2b(wv.w);
        }
      }
      *(uint4*)&Bs[arow][achunk * 16]     = *(uint4*)&tmp[0];
      *(uint4*)&Bs[arow][achunk * 16 + 8] = *(uint4*)&tmp[8];
    }
    __syncthreads();

    int kq = lane >> 4, mr = lane & 15;
    short8 af[4], bf[4];
    #pragma unroll
    for (int i = 0; i < 4; i++) af[i] = *(const short8*)&As[wm*64 + i*16 + mr][kq*8];
    #pragma unroll
    for (int j = 0; j < 4; j++) bf[j] = *(const short8*)&Bs[wn*64 + j*16 + mr][kq*8];
    #pragma unroll
    for (int i = 0; i < 4; i++)
      #pragma unroll
      for (int j = 0; j < 4; j++)
        acc[i][j] = __builtin_amdgcn_mfma_f32_16x16x32_bf16(af[i], bf[j], acc[i][j], 0, 0, 0);
  }

  int cr = lane >> 4, cc = lane & 15;
  #pragma unroll
  for (int j = 0; j < 4; j++){
    int col = bn * 128 + wn * 64 + j * 16 + cc;
    float bv = bias ? bias[col] : 0.f;
    #pragma unroll
    for (int i = 0; i < 4; i++){
      #pragma unroll
      for (int r = 0; r < 4; r++){
        int row = bm * 128 + wm * 64 + i * 16 + cr * 4 + r;
        float v = acc[i][j][r] * s + bv;
        if (relu) v = fmaxf(v, 0.f);
        size_t idx = (size_t)row * N + col;
        if (outf) outf[idx] = v;
        if (outb) outb[idx] = f2b(v);
      }
    }
  }
}

// ---------------- split-K bf16 MFMA GEMM (128x128 tile, grid.z = K-slices) ----------------
template<int WM>
__global__ __launch_bounds__(256) void gemm_ks_t(
    const unsigned short* __restrict__ A, const void* __restrict__ Wp,
    const float* __restrict__ bias, const double* __restrict__ ssum, double cnt,
    float* __restrict__ p0, float* __restrict__ pext,
    int M, int N, int K, int Klen)
{
  __shared__ unsigned short As[128][40];
  __shared__ unsigned short Bs[128][40];
  int tid = threadIdx.x;
  int wave = tid >> 6, lane = tid & 63;
  int wm = wave >> 1, wn = wave & 1;
  int bm = blockIdx.y, bn = blockIdx.x, z = blockIdx.z;

  float s = 1.f, T = 0.f;
  if (ssum){
    double s64 = ssum[0] / cnt + 1e-8;
    s = (float)s64;
    T = tern_thresh(s64);
  }

  int arow = tid >> 1, achunk = tid & 1;
  int kbase = z * Klen;
  const unsigned short* Ag = A + (size_t)(bm * 128 + arow) * K + kbase + achunk * 16;
  const float* Wg32 = (const float*)Wp + (size_t)(bn * 128 + arow) * K + kbase + achunk * 16;
  const unsigned short* Wg16 = (const unsigned short*)Wp + (size_t)(bn * 128 + arow) * K + kbase + achunk * 16;

  floatx4 acc[4][4];
  #pragma unroll
  for (int i = 0; i < 4; i++)
    #pragma unroll
    for (int j = 0; j < 4; j++)
      acc[i][j] = (floatx4){0.f, 0.f, 0.f, 0.f};

  for (int k0 = 0; k0 < Klen; k0 += 32){
    __syncthreads();
    uint4 a0 = *(const uint4*)(Ag + k0);
    uint4 a1 = *(const uint4*)(Ag + k0 + 8);
    *(uint4*)&As[arow][achunk * 16]     = a0;
    *(uint4*)&As[arow][achunk * 16 + 8] = a1;
    if (WM == 2){
      uint4 b0 = *(const uint4*)(Wg16 + k0);
      uint4 b1 = *(const uint4*)(Wg16 + k0 + 8);
      *(uint4*)&Bs[arow][achunk * 16]     = b0;
      *(uint4*)&Bs[arow][achunk * 16 + 8] = b1;
    } else {
      unsigned short tmp[16];
      #pragma unroll
      for (int q = 0; q < 4; q++){
        float4 wv = *(const float4*)(Wg32 + k0 + q * 4);
        tmp[q*4+0] = (wv.x > T) ? 0x3F80 : ((wv.x < -T) ? 0xBF80 : 0);
        tmp[q*4+1] = (wv.y > T) ? 0x3F80 : ((wv.y < -T) ? 0xBF80 : 0);
        tmp[q*4+2] = (wv.z > T) ? 0x3F80 : ((wv.z < -T) ? 0xBF80 : 0);
        tmp[q*4+3] = (wv.w > T) ? 0x3F80 : ((wv.w < -T) ? 0xBF80 : 0);
      }
      *(uint4*)&Bs[arow][achunk * 16]     = *(uint4*)&tmp[0];
      *(uint4*)&Bs[arow][achunk * 16 + 8] = *(uint4*)&tmp[8];
    }
    __syncthreads();

    int kq = lane >> 4, mr = lane & 15;
    short8 af[4], bf[4];
    #pragma unroll
    for (int i = 0; i < 4; i++) af[i] = *(const short8*)&As[wm*64 + i*16 + mr][kq*8];
    #pragma unroll
    for (int j = 0; j < 4; j++) bf[j] = *(const short8*)&Bs[wn*64 + j*16 + mr][kq*8];
    #pragma unroll
    for (int i = 0; i < 4; i++)
      #pragma unroll
      for (int j = 0; j < 4; j++)
        acc[i][j] = __builtin_amdgcn_mfma_f32_16x16x32_bf16(af[i], bf[j], acc[i][j], 0, 0, 0);
  }

  float* outp = (z == 0) ? p0 : pext + (size_t)(z - 1) * M * N;
  int cr = lane >> 4, cc = lane & 15;
  #pragma unroll
  for (int j = 0; j < 4; j++){
    int col = bn * 128 + wn * 64 + j * 16 + cc;
    float bv = (z == 0 && bias) ? bias[col] : 0.f;
    #pragma unroll
    for (int i = 0; i < 4; i++){
      #pragma unroll
      for (int r = 0; r < 4; r++){
        int row = bm * 128 + wm * 64 + i * 16 + cr * 4 + r;
        outp[(size_t)row * N + col] = acc[i][j][r] * s + bv;
      }
    }
  }
}

// ---------------- bf16 MFMA GEMM (256x128 tile, 512 threads) ----------------
template<int WM>
__global__ __launch_bounds__(512) void gemm256_t(
    const unsigned short* __restrict__ A, const void* __restrict__ Wp,
    const float* __restrict__ bias, const double* __restrict__ ssum, double cnt,
    int relu, float* __restrict__ outf, unsigned short* __restrict__ outb,
    int M, int N, int K)
{
  __shared__ unsigned short As[256][40];
  __shared__ unsigned short Bs[128][40];
  int tid = threadIdx.x;
  int wave = tid >> 6, lane = tid & 63;
  int wm = wave >> 1, wn = wave & 1;   // wm 0..3, wn 0..1
  int bm = blockIdx.y, bn = blockIdx.x;

  float s = 1.f, T = 0.f;
  if (ssum){
    double s64 = ssum[0] / cnt + 1e-8;
    s = (float)s64;
    T = tern_thresh(s64);
  }

  int arow = tid >> 1, achunk = tid & 1;          // 256 rows x 2 chunks of 16
  int wrow = tid >> 2, wchunk = tid & 3;          // 128 rows x 4 chunks of 8
  const unsigned short* Ag = A + (size_t)(bm * 256 + arow) * K + achunk * 16;
  const float* Wg32 = (const float*)Wp + (size_t)(bn * 128 + wrow) * K + wchunk * 8;
  const unsigned short* Wg16 = (const unsigned short*)Wp + (size_t)(bn * 128 + wrow) * K + wchunk * 8;

  floatx4 acc[4][4];
  #pragma unroll
  for (int i = 0; i < 4; i++)
    #pragma unroll
    for (int j = 0; j < 4; j++)
      acc[i][j] = (floatx4){0.f, 0.f, 0.f, 0.f};

  for (int k0 = 0; k0 < K; k0 += 32){
    __syncthreads();
    uint4 a0 = *(const uint4*)(Ag + k0);
    uint4 a1 = *(const uint4*)(Ag + k0 + 8);
    *(uint4*)&As[arow][achunk * 16]     = a0;
    *(uint4*)&As[arow][achunk * 16 + 8] = a1;
    if (WM == 2){
      uint4 b0 = *(const uint4*)(Wg16 + k0);
      *(uint4*)&Bs[wrow][wchunk * 8] = b0;
    } else {
      unsigned short tmp[8];
      float4 w0 = *(const float4*)(Wg32 + k0);
      float4 w1 = *(const float4*)(Wg32 + k0 + 4);
      if (WM == 1){
        tmp[0] = (w0.x > T) ? 0x3F80 : ((w0.x < -T) ? 0xBF80 : 0);
        tmp[1] = (w0.y > T) ? 0x3F80 : ((w0.y < -T) ? 0xBF80 : 0);
        tmp[2] = (w0.z > T) ? 0x3F80 : ((w0.z < -T) ? 0xBF80 : 0);
        tmp[3] = (w0.w > T) ? 0x3F80 : ((w0.w < -T) ? 0xBF80 : 0);
        tmp[4] = (w1.x > T) ? 0x3F80 : ((w1.x < -T) ? 0xBF80 : 0);
        tmp[5] = (w1.y > T) ? 0x3F80 : ((w1.y < -T) ? 0xBF80 : 0);
        tmp[6] = (w1.z > T) ? 0x3F80 : ((w1.z < -T) ? 0xBF80 : 0);
        tmp[7] = (w1.w > T) ? 0x3F80 : ((w1.w < -T) ? 0xBF80 : 0);
      } else {
        tmp[0] = f2b(w0.x); tmp[1] = f2b(w0.y); tmp[2] = f2b(w0.z); tmp[3] = f2b(w0.w);
        tmp[4] = f2b(w1.x); tmp[5] = f2b(w1.y); tmp[6] = f2b(w1.z); tmp[7] = f2b(w1.w);
      }
      *(uint2*)&Bs[wrow][wchunk * 8]     = *(uint2*)&tmp[0];
      *(uint2*)&Bs[wrow][wchunk * 8 + 4] = *(uint2*)&tmp[4];
    }
    __syncthreads();

    int kq = lane >> 4, mr = lane & 15;
    short8 af[4], bf[4];
    #pragma unroll
    for (int i = 0; i < 4; i++) af[i] = *(const short8*)&As[wm*64 + i*16 + mr][kq*8];
    #pragma unroll
    for (int j = 0; j < 4; j++) bf[j] = *(const short8*)&Bs[wn*64 + j*16 + mr][kq*8];
    #pragma unroll
    for (int i = 0; i < 4; i++)
      #pragma unroll
      for (int j = 0; j < 4; j++)
        acc[i][j] = __builtin_amdgcn_mfma_f32_16x16x32_bf16(af[i], bf[j], acc[i][j], 0, 0, 0);
  }

  int cr = lane >> 4, cc = lane & 15;
  #pragma unroll
  for (int j = 0; j < 4; j++){
    int col = bn * 128 + wn * 64 + j * 16 + cc;
    float bv = bias ? bias[col] : 0.f;
    #pragma unroll
    for (int i = 0; i < 4; i++){
      #pragma unroll
      for (int r = 0; r < 4; r++){
        int row = bm * 256 + wm * 64 + i * 16 + cr * 4 + r;
        float v = acc[i][j][r] * s + bv;
        if (relu) v = fmaxf(v, 0.f);
        size_t idx = (size_t)row * N + col;
        if (outf) outf[idx] = v;
        if (outb) outb[idx] = f2b(v);
      }
    }
  }
}

// ---------------- prep pointers for in-GRU weave ----------------
struct PrepPtrs { const float* src[9]; unsigned short* dst[9]; };

// ---------------- persistent GRU with step-woven weight prep ----------------
// Identical to round 12 except the gather-poll sleep quantum: s_sleep(2) ->
// s_sleep(8). 131072 pollers x 2 entries at 50ns offered ~5e12 req/s to a
// 16KB MALL window -> request queueing inflates detection RTT on the chained
// global sync (paid 512x). Sleep(8) cuts offered load 4x for +~100ns
// detection granularity. All arithmetic/protocol unchanged (bit-exact h).
template<bool PREP>
__global__ __launch_bounds__(512) void gru_prep_kernel(
    const float* __restrict__ gi, const float* __restrict__ whh, const float* __restrict__ bhh,
    unsigned long long* __restrict__ hbuf,
    float* __restrict__ hs, unsigned short* __restrict__ hsb,
    PrepPtrs pp, double* __restrict__ parts, double* __restrict__ scales)
{
  __shared__ __align__(16) float lds_h[2][Dm];
  __shared__ float lds_gh[24];
  __shared__ double lds_aux[16];
  int w = blockIdx.x, tid = threadIdx.x;
  int bb = w & 1, slice = w >> 1;     // slice in [0,128)
  int d0 = slice * 8;
  int o = tid >> 4, c = tid & 15;     // dot o (24 dots), k-chunk c
  bool active = (o < 24);
  int g = o >> 3, dl = o & 7;         // gate, local dim
  int wrow = g * Dm + d0 + dl;
  float4 wr0 = {0,0,0,0}, wr1 = wr0, wr2 = wr0, wr3 = wr0,
         wr4 = wr0, wr5 = wr0, wr6 = wr0, wr7 = wr0,
         wr8 = wr0, wr9 = wr0, wr10 = wr0, wr11 = wr0,
         wr12 = wr0, wr13 = wr0, wr14 = wr0, wr15 = wr0;
  if (active){
    const float* wsrc = whh + (size_t)wrow * Dm + c * 4;
    wr0  = *(const float4*)(wsrc +  0*64);  wr1  = *(const float4*)(wsrc +  1*64);
    wr2  = *(const float4*)(wsrc +  2*64);  wr3  = *(const float4*)(wsrc +  3*64);
    wr4  = *(const float4*)(wsrc +  4*64);  wr5  = *(const float4*)(wsrc +  5*64);
    wr6  = *(const float4*)(wsrc +  6*64);  wr7  = *(const float4*)(wsrc +  7*64);
    wr8  = *(const float4*)(wsrc +  8*64);  wr9  = *(const float4*)(wsrc +  9*64);
    wr10 = *(const float4*)(wsrc + 10*64);  wr11 = *(const float4*)(wsrc + 11*64);
    wr12 = *(const float4*)(wsrc + 12*64);  wr13 = *(const float4*)(wsrc + 13*64);
    wr14 = *(const float4*)(wsrc + 14*64);  wr15 = *(const float4*)(wsrc + 15*64);
  }
  float bhval = (active && c == 0) ? bhh[wrow] : 0.f;

  int gidx = tid * 2;                 // this thread's 2 packed entries (own batch)
  bool self = ((tid >> 2) == slice);  // own window [8*slice, 8*slice+8)
  int dd = tid;                       // only meaningful for tid<8
  int dth = d0 + (tid & 7);
  float pir = 0.f, piz = 0.f, pin = 0.f;
  if (tid < 8){
    const float* girow = gi + (size_t)bb * Sm * (3 * Dm);
    pir = girow[dth]; piz = girow[Dm + dth]; pin = girow[2*Dm + dth];
  }

  // ---- prep state ----
  int myslot = 0, iters = 0, nthr = 0;
  const float4* psrc = nullptr;
  ushort4* pdst = nullptr;
  double acc = 0.0, fin = 0.0;
  float4 pend = {0.f, 0.f, 0.f, 0.f};
  float Tq = 0.f;
  int pbase = 0, npar = 0;
  double mycnt = 1.0;
  if (PREP){
    int rank;
    if (w < 128){ myslot = w >> 4; rank = ((w & 15) << 9) | tid; nthr = 8192;  iters = 128; }
    else        { myslot = 8;      rank = ((w - 128) << 9) | tid; nthr = 65536; iters = 125; }
    psrc = (const float4*)pp.src[myslot] + rank;
    pdst = (ushort4*)pp.dst[myslot] + rank;
    pbase = (w < 8) ? w * 16 : 128;
    npar  = (w < 8) ? 16 : 128;
    mycnt = (myslot == 8) ? (double)Vm * (double)Dm : (double)Nm * (double)Dm;
    pend = psrc[0];                   // prefetch absum element 0
  }

  for (int t = 0; t < Sm; t++){
    if (PREP){
      if (t < iters){
        acc += (double)fabsf(pend.x) + (double)fabsf(pend.y)
             + (double)fabsf(pend.z) + (double)fabsf(pend.w);
        if (t + 1 < iters) pend = psrc[(size_t)(t + 1) * nthr];
      } else if (t == 132){
        double r = acc;
        #pragma unroll
        for (int off = 32; off; off >>= 1) r += __shfl_down(r, off, 64);
        if ((tid & 63) == 0) lds_aux[tid >> 6] = r;
        __syncthreads();              // t-uniform -> safe
        if (tid == 0){
          double tot = 0.0;
          #pragma unroll
          for (int i = 0; i < 8; i++) tot += lds_aux[i];
          __hip_atomic_store(&parts[w], tot, __ATOMIC_RELAXED, __HIP_MEMORY_SCOPE_AGENT);
        }
      } else if (t >= 140 && t < 268){
        if (w <= 8 && tid == 0 && (t - 140) < npar)
          fin += __hip_atomic_load(&parts[pbase + (t - 140)],
                                   __ATOMIC_RELAXED, __HIP_MEMORY_SCOPE_AGENT);
      } else if (t == 272){
        if (w <= 8 && tid == 0)
          __hip_atomic_store(&scales[1 + w], fin, __ATOMIC_RELAXED, __HIP_MEMORY_SCOPE_AGENT);
      } else if (t == 280){
        if (tid == 0)
          lds_aux[9] = __hip_atomic_load(&scales[1 + myslot],
                                         __ATOMIC_RELAXED, __HIP_MEMORY_SCOPE_AGENT);
      } else if (t == 284){
        double s64 = lds_aux[9] / mycnt + 1e-8;   // lds_aux[9] sync'd by step barriers
        Tq = tern_thresh(s64);
        pend = psrc[0];               // prefetch pack element 0
      } else if (t >= 288 && t < 288 + iters){
        int k = t - 288;
        ushort4 u;
        u.x = (pend.x > Tq) ? 0x3F80 : ((pend.x < -Tq) ? 0xBF80 : 0);
        u.y = (pend.y > Tq) ? 0x3F80 : ((pend.y < -Tq) ? 0xBF80 : 0);
        u.z = (pend.z > Tq) ? 0x3F80 : ((pend.z < -Tq) ? 0xBF80 : 0);
        u.w = (pend.w > Tq) ? 0x3F80 : ((pend.w < -Tq) ? 0xBF80 : 0);
        pdst[(size_t)k * nthr] = u;
        if (k + 1 < iters) pend = psrc[(size_t)(k + 1) * nthr];
      }
    }

    float* lh = lds_h[t & 1];
    if (!self || t == 0){
      const unsigned long long* hsrc = hbuf + (size_t)(t & 1) * 2048 + bb * 1024 + gidx;
      const unsigned long long* xsrc = hbuf + (size_t)(t & 1) * 2048 + (1 - bb) * 1024;
      unsigned long long e0, e1;
      int spins = 0;
      for (;;){
        e0 = __hip_atomic_load(hsrc + 0, __ATOMIC_RELAXED, __HIP_MEMORY_SCOPE_AGENT);
        e1 = __hip_atomic_load(hsrc + 1, __ATOMIC_RELAXED, __HIP_MEMORY_SCOPE_AGENT);
        bool ok = ((unsigned)(e0 >> 32) == (unsigned)t) &&
                  ((unsigned)(e1 >> 32) == (unsigned)t);
        if (PREP && tid == 256){      // cross-batch coupling (provable lockstep)
          unsigned long long ex =
              __hip_atomic_load(xsrc, __ATOMIC_RELAXED, __HIP_MEMORY_SCOPE_AGENT);
          ok = ok && ((unsigned)(ex >> 32) == (unsigned)t);
        }
        if (ok) break;
        __builtin_amdgcn_s_sleep(8);
        if (++spins > (1 << 16)) break;   // safety: degrade, don't hang
      }
      lh[gidx + 0] = __uint_as_float((unsigned)e0);
      lh[gidx + 1] = __uint_as_float((unsigned)e1);
    }
    __syncthreads();   // sync A: lds_h[t&1] complete
    float dacc = 0.f;
    if (active){
      const float* hb = lh + c * 4;
      float4 hv;
      #define GDOT(J, W) hv = *(const float4*)(hb + (J)*64); \
          dacc += W.x*hv.x + W.y*hv.y + W.z*hv.z + W.w*hv.w;
      GDOT(0,wr0)  GDOT(1,wr1)  GDOT(2,wr2)  GDOT(3,wr3)
      GDOT(4,wr4)  GDOT(5,wr5)  GDOT(6,wr6)  GDOT(7,wr7)
      GDOT(8,wr8)  GDOT(9,wr9)  GDOT(10,wr10) GDOT(11,wr11)
      GDOT(12,wr12) GDOT(13,wr13) GDOT(14,wr14) GDOT(15,wr15)
      #undef GDOT
    }
    #pragma unroll
    for (int off = 8; off; off >>= 1) dacc += __shfl_xor(dacc, off, 16);
    if (active && c == 0) lds_gh[o] = dacc + bhval;
    __syncthreads();   // sync B: gates ready
    if (tid < 8){
      float gr = lds_gh[dd];
      float gz = lds_gh[8 + dd];
      float gn = lds_gh[16 + dd];
      float hv = lh[dth];
      float rr = 1.f / (1.f + expf(-(pir + gr)));
      float zz = 1.f / (1.f + expf(-(piz + gz)));
      float nn = tanhf(pin + rr * gn);
      float hnew = (1.f - zz) * nn + zz * hv;
      unsigned long long pack =
          ((unsigned long long)(unsigned)(t + 1) << 32) | (unsigned long long)__float_as_uint(hnew);
      __hip_atomic_store(hbuf + (size_t)((t + 1) & 1) * 2048 + bb * 1024 + dth, pack,
                         __ATOMIC_RELAXED, __HIP_MEMORY_SCOPE_AGENT);
      lds_h[(t + 1) & 1][dth] = hnew;
      if (t + 1 < Sm){
        const float* girow = gi + ((size_t)bb * Sm + (t+1)) * (3 * Dm);
        pir = girow[dth]; piz = girow[Dm + dth]; pin = girow[2*Dm + dth];
      }
      size_t oi = ((size_t)bb * Sm + t) * Dm + dth;
      hs[oi]  = hnew;
      hsb[oi] = f2b(hnew);
    }
  }
}

// ---------------- layernorm (+residual + up to 4 split-K partials) ----------------
__global__ __launch_bounds__(256) void ln_kernel(
    float* __restrict__ resid, const float* __restrict__ p0,
    const float* __restrict__ pext,
    const float* __restrict__ g, const float* __restrict__ b,
    float* __restrict__ outf, unsigned short* __restrict__ outb)
{
  int row = blockIdx.x;
  int d = threadIdx.x * 4;
  size_t base = (size_t)row * Dm + d;
  float4 v = *(float4*)(resid + base);
  if (p0){
    float4 a = *(const float4*)(p0 + base);
    v.x += a.x; v.y += a.y; v.z += a.z; v.w += a.w;
  }
  if (pext){
    const size_t stride = (size_t)1024 * Dm;
    #pragma unroll
    for (int e = 0; e < 3; e++){
      float4 a = *(const float4*)(pext + e * stride + base);
      v.x += a.x; v.y += a.y; v.z += a.z; v.w += a.w;
    }
  }
  float sum = v.x + v.y + v.z + v.w;
  float sq  = v.x*v.x + v.y*v.y + v.z*v.z + v.w*v.w;
  #pragma unroll
  for (int off = 32; off; off >>= 1){
    sum += __shfl_down(sum, off, 64);
    sq  += __shfl_down(sq,  off, 64);
  }
  __shared__ float red[4][2];
  __shared__ float bc[2];
  int lane = threadIdx.x & 63, wv = threadIdx.x >> 6;
  if (lane == 0){ red[wv][0] = sum; red[wv][1] = sq; }
  __syncthreads();
  if (threadIdx.x == 0){
    float st = red[0][0] + red[1][0] + red[2][0] + red[3][0];
    float qt = red[0][1] + red[1][1] + red[2][1] + red[3][1];
    float mu = st * (1.f / Dm);
    float var = qt * (1.f / Dm) - mu * mu;
    bc[0] = mu; bc[1] = rsqrtf(var + 1e-5f);
  }
  __syncthreads();
  float mu = bc[0], rs = bc[1];
  float4 gv = *(const float4*)(g + d);
  float4 bv = *(const float4*)(b + d);
  float4 y;
  y.x = (v.x - mu) * rs * gv.x + bv.x;
  y.y = (v.y - mu) * rs * gv.y + bv.y;
  y.z = (v.z - mu) * rs * gv.z + bv.z;
  y.w = (v.w - mu) * rs * gv.w + bv.w;
  if (outf) *(float4*)(outf + base) = y;
  if (outb){
    ushort4 u = make_ushort4(f2b(y.x), f2b(y.y), f2b(y.z), f2b(y.w));
    *(ushort4*)(outb + base) = u;
  }
}

extern "C" void kernel_launch(void* const* d_in, const int* in_sizes, int n_in,
                              void* d_out, int out_size, void* d_ws, size_t ws_size,
                              hipStream_t stream)
{
  const int*   ids    = (const int*)  d_in[0];
  const float* emb    = (const float*)d_in[1];
  const float* pos    = (const float*)d_in[2];
  const float* wih    = (const float*)d_in[3];
  const float* whh    = (const float*)d_in[4];
  const float* bih    = (const float*)d_in[5];
  const float* bhh    = (const float*)d_in[6];
  const float* syn_w  = (const float*)d_in[7];
  const float* syn_b  = (const float*)d_in[8];
  const float* out_w  = (const float*)d_in[9];
  const float* out_b  = (const float*)d_in[10];
  const float* ln_g   = (const float*)d_in[11];
  const float* ln_b   = (const float*)d_in[12];
  const float* on_g   = (const float*)d_in[13];
  const float* on_b   = (const float*)d_in[14];
  const float* head_w = (const float*)d_in[15];
  const float* head_b = (const float*)d_in[16];
  float* logits = (float*)d_out;

  char* ws = (char*)d_ws;
  double*             scales = (double*)ws;                         // 10 doubles
  unsigned long long* hbuf   = (unsigned long long*)(ws + 4096);    // 2*2048 packed {tag,h} (32KB)
  double*             parts  = (double*)(ws + 36864);               // 512 doubles used (4KB of 40KB)
  unsigned short*     xb     = (unsigned short*)(ws + 131072);      // [1024,1024] bf16 (2MB)
  float*              hs     = (float*)(ws + ((size_t)4  << 20));   // [1024,1024] f32  (4MB)
  unsigned short*     hidden = (unsigned short*)(ws + ((size_t)12 << 20)); // [1024,4096] bf16 (8MB)
  float*              outbuf = (float*)(ws + ((size_t)20 << 20));   // [1024,1024] f32  (4MB)
  float*              gi     = (float*)(ws + ((size_t)24 << 20));   // [1024,3072] f32  (12MB; split-K partials after GRU)
  // packed bf16 weights (guarded by ws_size)
  unsigned short*     wih_b  = (unsigned short*)(ws + ((size_t)36 << 20));  // 6MB
  unsigned short*     syn_bk = (unsigned short*)(ws + ((size_t)42 << 20));  // 32MB
  unsigned short*     out_bk = (unsigned short*)(ws + ((size_t)74 << 20));  // 32MB
  unsigned short*     head_bk= (unsigned short*)(ws + ((size_t)106 << 20)); // 62.5MB
  const size_t NEED = ((size_t)106 << 20) + (size_t)Vm * Dm * 2;
  const bool packed = (ws_size >= NEED);

  // zero scales + hbuf + parts head (tags=0 == initial h state for t=0)
  hipMemsetAsync(d_ws, 0, 36864, stream);

  const double cnt_nd = (double)Nm * (double)Dm;
  const double cnt_vd = (double)Vm * (double)Dm;

  if (packed){
    // pre-GRU: only emb scale (for embed) + wih pack (for gi GEMM)
    AbsumArgs aa; aa.src[0] = emb; aa.n4[0] = (long)Vm * Dm / 4;
    absum_all_kernel<<<dim3(512, 1), 256, 0, stream>>>(aa, parts);
    absum_final_kernel<<<1, 256, 0, stream>>>(parts, scales);
    PackArgs pw;
    pw.src[0] = wih; pw.dst[0] = wih_b; pw.n4[0] = (long)(3*Dm)*Dm/4;
    pw.sidx[0] = -1; pw.cnt[0] = 1.0;
    pack_all_kernel<<<dim3(512, 1), 256, 0, stream>>>(pw, scales);
  } else {
    // fallback: full serial absum over all 10 slots (no packing)
    AbsumArgs aa;
    aa.src[0] = emb;    aa.n4[0] = (long)Vm * Dm / 4;
    for (int l = 0; l < Lm; l++){
      aa.src[1 + l] = syn_w + (size_t)l * Nm * Dm; aa.n4[1 + l] = (long)Nm * Dm / 4;
      aa.src[5 + l] = out_w + (size_t)l * Dm * Nm; aa.n4[5 + l] = (long)Nm * Dm / 4;
    }
    aa.src[9] = head_w; aa.n4[9] = (long)Vm * Dm / 4;
    absum_all_kernel<<<dim3(512, 10), 256, 0, stream>>>(aa, parts);
    absum_final_kernel<<<10, 256, 0, stream>>>(parts, scales);
  }

  // x = tern(emb)[ids] + pos  (bf16)
  embed_kernel<<<1024, 256, 0, stream>>>(ids, emb, pos, scales, xb);

  // gi = x @ wih^T + bih
  if (packed)
    gemm_t<2><<<dim3(3072/128, 1024/128), 256, 0, stream>>>(
        xb, wih_b, bih, nullptr, 0.0, 0, gi, nullptr, 1024, 3072, 1024);
  else
    gemm_t<0><<<dim3(3072/128, 1024/128), 256, 0, stream>>>(
        xb, wih, bih, nullptr, 0.0, 0, gi, nullptr, 1024, 3072, 1024);

  // sequential GRU with step-woven syn/out/head scale+pack
  {
    PrepPtrs pp;
    for (int l = 0; l < Lm; l++){
      pp.src[l]     = syn_w + (size_t)l * Nm * Dm; pp.dst[l]     = syn_bk + (size_t)l * Nm * Dm;
      pp.src[4 + l] = out_w + (size_t)l * Dm * Nm; pp.dst[4 + l] = out_bk + (size_t)l * Dm * Nm;
    }
    pp.src[8] = head_w; pp.dst[8] = head_bk;
    if (packed)
      gru_prep_kernel<true><<<256, 512, 0, stream>>>(gi, whh, bhh, hbuf, hs, xb,
                                                     pp, parts, scales);
    else
      gru_prep_kernel<false><<<256, 512, 0, stream>>>(gi, whh, bhh, hbuf, hs, xb,
                                                      pp, parts, scales);
  }

  for (int l = 0; l < Lm; l++){
    // hidden = relu(x @ tern(syn_w)^T + syn_b)  (bf16)
    if (packed)
      gemm_t<2><<<dim3(4096/128, 1024/128), 256, 0, stream>>>(
          xb, syn_bk + (size_t)l * Nm * Dm, syn_b + (size_t)l * Nm,
          scales + 1 + l, cnt_nd, 1, nullptr, hidden, 1024, 4096, 1024);
    else
      gemm_t<1><<<dim3(4096/128, 1024/128), 256, 0, stream>>>(
          xb, syn_w + (size_t)l * Nm * Dm, syn_b + (size_t)l * Nm,
          scales + 1 + l, cnt_nd, 1, nullptr, hidden, 1024, 4096, 1024);
    // out partials = hidden @ tern(out_w)^T (split-K=4)
    if (packed)
      gemm_ks_t<2><<<dim3(1024/128, 1024/128, 4), 256, 0, stream>>>(
          hidden, out_bk + (size_t)l * Dm * Nm, out_b + (size_t)l * Dm,
          scales + 5 + l, cnt_nd, outbuf, gi, 1024, 1024, 4096, 1024);
    else
      gemm_ks_t<1><<<dim3(1024/128, 1024/128, 4), 256, 0, stream>>>(
          hidden, out_w + (size_t)l * Dm * Nm, out_b + (size_t)l * Dm,
          scales + 5 + l, cnt_nd, outbuf, gi, 1024, 1024, 4096, 1024);
    // x = LN(resid + sum of partials)  -> hs (f32) and xb (bf16)
    ln_kernel<<<1024, 256, 0, stream>>>(hs, outbuf, gi,
        ln_g + (size_t)l * Dm, ln_b + (size_t)l * Dm, hs, xb);
  }
  // final LN -> xb (bf16)
  ln_kernel<<<1024, 256, 0, stream>>>(hs, nullptr, nullptr, on_g, on_b, nullptr, xb);

  // logits = x @ tern(head_w)^T + head_b  (f32 -> d_out), 256-row tiles
  if (packed)
    gemm256_t<2><<<dim3(32000/128, 1024/256), 512, 0, stream>>>(
        xb, head_bk, head_b, scales + 9, cnt_vd, 0, logits, nullptr, 1024, 32000, 1024);
  else
    gemm256_t<1><<<dim3(32000/128, 1024/256), 512, 0, stream>>>(
        xb, head_w, head_b, scales + 9, cnt_vd, 0, logits, nullptr, 1024, 32000, 1024);
}

// Round 14
// 1969.259 us; speedup vs baseline: 1.0280x; 1.0280x over previous
//
#include <hip/hip_runtime.h>
#include <hip/hip_bf16.h>
#include <cstdint>
#include <cstddef>

#define Dm 1024
#define Sm 512
#define Bm 2
#define Nm 4096
#define Lm 4
#define Vm 32000

typedef __attribute__((ext_vector_type(8))) short short8;
typedef __attribute__((ext_vector_type(4))) float floatx4;

__device__ __forceinline__ unsigned short f2b(float f){
  union { float f; unsigned u; } v; v.f = f;
  unsigned r = (v.u + 0x7fffu + ((v.u >> 16) & 1u)) >> 16;
  return (unsigned short)r;
}

// Exact f32 threshold for the ternary decision (see round-6 proof).
__device__ __forceinline__ float tern_thresh(double s64){
  float T = (float)(s64 * 0.5);
  if ((double)T > s64 * 0.5) T = __uint_as_float(__float_as_uint(T) - 1u);
  return T;
}

// ---------------- fused abs-sum (grid.y = slots) ----------------
struct AbsumArgs { const float* src[10]; long n4[10]; };

__global__ __launch_bounds__(256) void absum_all_kernel(
    AbsumArgs a, double* __restrict__ parts)
{
  int slot = blockIdx.y;
  const float* x = a.src[slot];
  long n4 = a.n4[slot];
  long i = (long)blockIdx.x * blockDim.x + threadIdx.x;
  long stride = (long)gridDim.x * blockDim.x;
  double s = 0.0;
  for (; i < n4; i += stride){
    float4 v = ((const float4*)x)[i];
    s += (double)fabsf(v.x) + (double)fabsf(v.y)
       + (double)fabsf(v.z) + (double)fabsf(v.w);
  }
  #pragma unroll
  for (int off = 32; off; off >>= 1) s += __shfl_down(s, off, 64);
  __shared__ double wsum[4];
  int lane = threadIdx.x & 63, wv = threadIdx.x >> 6;
  if (lane == 0) wsum[wv] = s;
  __syncthreads();
  if (threadIdx.x == 0)
    parts[(size_t)slot * 512 + blockIdx.x] = wsum[0]+wsum[1]+wsum[2]+wsum[3];
}

__global__ __launch_bounds__(256) void absum_final_kernel(
    const double* __restrict__ part, double* __restrict__ scales)
{
  const double* p = part + (size_t)blockIdx.x * 512;
  int tid = threadIdx.x;
  double s = p[tid] + p[tid + 256];
  #pragma unroll
  for (int off = 32; off; off >>= 1) s += __shfl_down(s, off, 64);
  __shared__ double wsum[4];
  int lane = tid & 63, wv = tid >> 6;
  if (lane == 0) wsum[wv] = s;
  __syncthreads();
  if (tid == 0) scales[blockIdx.x] = wsum[0]+wsum[1]+wsum[2]+wsum[3];
}

// ---------------- fused weight pre-pack (grid.y = slots) ----------------
struct PackArgs {
  const float* src[10]; unsigned short* dst[10];
  long n4[10]; int sidx[10]; double cnt[10];
};

__global__ __launch_bounds__(256) void pack_all_kernel(
    PackArgs a, const double* __restrict__ scales)
{
  int slot = blockIdx.y;
  const float* src = a.src[slot];
  unsigned short* dst = a.dst[slot];
  long n4 = a.n4[slot];
  bool tern = (a.sidx[slot] >= 0);
  float T = 0.f;
  if (tern){
    double s64 = scales[a.sidx[slot]] / a.cnt[slot] + 1e-8;
    T = tern_thresh(s64);
  }
  long i = (long)blockIdx.x * blockDim.x + threadIdx.x;
  long stride = (long)gridDim.x * blockDim.x;
  for (; i < n4; i += stride){
    float4 v = ((const float4*)src)[i];
    ushort4 u;
    if (tern){
      u.x = (v.x > T) ? 0x3F80 : ((v.x < -T) ? 0xBF80 : 0);
      u.y = (v.y > T) ? 0x3F80 : ((v.y < -T) ? 0xBF80 : 0);
      u.z = (v.z > T) ? 0x3F80 : ((v.z < -T) ? 0xBF80 : 0);
      u.w = (v.w > T) ? 0x3F80 : ((v.w < -T) ? 0xBF80 : 0);
    } else {
      u.x = f2b(v.x); u.y = f2b(v.y); u.z = f2b(v.z); u.w = f2b(v.w);
    }
    ((ushort4*)dst)[i] = u;
  }
}

// ---------------- ternary embedding + positional ----------------
__global__ __launch_bounds__(256) void embed_kernel(
    const int* __restrict__ ids, const float* __restrict__ emb,
    const float* __restrict__ pos, const double* __restrict__ ssum,
    unsigned short* __restrict__ xb)
{
  int row = blockIdx.x;            // b*512 + s
  int sp  = row & (Sm - 1);
  int id  = ids[row];
  double s64 = ssum[0] / ((double)Vm * (double)Dm) + 1e-8;
  float s = (float)s64;
  float T = tern_thresh(s64);
  int d = threadIdx.x * 4;
  float4 wv = *(const float4*)(emb + (size_t)id * Dm + d);
  float4 pv = *(const float4*)(pos + (size_t)sp * Dm + d);
  float q0 = (wv.x > T) ? 1.f : ((wv.x < -T) ? -1.f : 0.f);
  float q1 = (wv.y > T) ? 1.f : ((wv.y < -T) ? -1.f : 0.f);
  float q2 = (wv.z > T) ? 1.f : ((wv.z < -T) ? -1.f : 0.f);
  float q3 = (wv.w > T) ? 1.f : ((wv.w < -T) ? -1.f : 0.f);
  float y0 = s * q0 + pv.x;
  float y1 = s * q1 + pv.y;
  float y2 = s * q2 + pv.z;
  float y3 = s * q3 + pv.w;
  ushort4 u = make_ushort4(f2b(y0), f2b(y1), f2b(y2), f2b(y3));
  *(ushort4*)(xb + (size_t)row * Dm + d) = u;
}

// ---------------- bf16 MFMA GEMM (128x128 tile) ----------------
// WM = 0: W f32 plain | 1: W f32 ternary | 2: W bf16 pre-packed.
template<int WM>
__global__ __launch_bounds__(256) void gemm_t(
    const unsigned short* __restrict__ A, const void* __restrict__ Wp,
    const float* __restrict__ bias, const double* __restrict__ ssum, double cnt,
    int relu, float* __restrict__ outf, unsigned short* __restrict__ outb,
    int M, int N, int K)
{
  __shared__ unsigned short As[128][40];
  __shared__ unsigned short Bs[128][40];
  int tid = threadIdx.x;
  int wave = tid >> 6, lane = tid & 63;
  int wm = wave >> 1, wn = wave & 1;
  int bm = blockIdx.y, bn = blockIdx.x;

  float s = 1.f, T = 0.f;
  if (ssum){
    double s64 = ssum[0] / cnt + 1e-8;
    s = (float)s64;
    T = tern_thresh(s64);
  }

  int arow = tid >> 1, achunk = tid & 1;
  const unsigned short* Ag = A + (size_t)(bm * 128 + arow) * K + achunk * 16;
  const float* Wg32 = (const float*)Wp + (size_t)(bn * 128 + arow) * K + achunk * 16;
  const unsigned short* Wg16 = (const unsigned short*)Wp + (size_t)(bn * 128 + arow) * K + achunk * 16;

  floatx4 acc[4][4];
  #pragma unroll
  for (int i = 0; i < 4; i++)
    #pragma unroll
    for (int j = 0; j < 4; j++)
      acc[i][j] = (floatx4){0.f, 0.f, 0.f, 0.f};

  for (int k0 = 0; k0 < K; k0 += 32){
    __syncthreads();
    uint4 a0 = *(const uint4*)(Ag + k0);
    uint4 a1 = *(const uint4*)(Ag + k0 + 8);
    *(uint4*)&As[arow][achunk * 16]     = a0;
    *(uint4*)&As[arow][achunk * 16 + 8] = a1;
    if (WM == 2){
      uint4 b0 = *(const uint4*)(Wg16 + k0);
      uint4 b1 = *(const uint4*)(Wg16 + k0 + 8);
      *(uint4*)&Bs[arow][achunk * 16]     = b0;
      *(uint4*)&Bs[arow][achunk * 16 + 8] = b1;
    } else {
      unsigned short tmp[16];
      #pragma unroll
      for (int q = 0; q < 4; q++){
        float4 wv = *(const float4*)(Wg32 + k0 + q * 4);
        if (WM == 1){
          tmp[q*4+0] = (wv.x > T) ? 0x3F80 : ((wv.x < -T) ? 0xBF80 : 0);
          tmp[q*4+1] = (wv.y > T) ? 0x3F80 : ((wv.y < -T) ? 0xBF80 : 0);
          tmp[q*4+2] = (wv.z > T) ? 0x3F80 : ((wv.z < -T) ? 0xBF80 : 0);
          tmp[q*4+3] = (wv.w > T) ? 0x3F80 : ((wv.w < -T) ? 0xBF80 : 0);
        } else {
          tmp[q*4+0] = f2b(wv.x); tmp[q*4+1] = f2b(wv.y);
          tmp[q*4+2] = f2b(wv.z); tmp[q*4+3] = f2b(wv.w);
        }
      }
      *(uint4*)&Bs[arow][achunk * 16]     = *(uint4*)&tmp[0];
      *(uint4*)&Bs[arow][achunk * 16 + 8] = *(uint4*)&tmp[8];
    }
    __syncthreads();

    int kq = lane >> 4, mr = lane & 15;
    short8 af[4], bf[4];
    #pragma unroll
    for (int i = 0; i < 4; i++) af[i] = *(const short8*)&As[wm*64 + i*16 + mr][kq*8];
    #pragma unroll
    for (int j = 0; j < 4; j++) bf[j] = *(const short8*)&Bs[wn*64 + j*16 + mr][kq*8];
    #pragma unroll
    for (int i = 0; i < 4; i++)
      #pragma unroll
      for (int j = 0; j < 4; j++)
        acc[i][j] = __builtin_amdgcn_mfma_f32_16x16x32_bf16(af[i], bf[j], acc[i][j], 0, 0, 0);
  }

  int cr = lane >> 4, cc = lane & 15;
  #pragma unroll
  for (int j = 0; j < 4; j++){
    int col = bn * 128 + wn * 64 + j * 16 + cc;
    float bv = bias ? bias[col] : 0.f;
    #pragma unroll
    for (int i = 0; i < 4; i++){
      #pragma unroll
      for (int r = 0; r < 4; r++){
        int row = bm * 128 + wm * 64 + i * 16 + cr * 4 + r;
        float v = acc[i][j][r] * s + bv;
        if (relu) v = fmaxf(v, 0.f);
        size_t idx = (size_t)row * N + col;
        if (outf) outf[idx] = v;
        if (outb) outb[idx] = f2b(v);
      }
    }
  }
}

// ---------------- split-K bf16 MFMA GEMM (128x128 tile, grid.z = K-slices) ----------------
template<int WM>
__global__ __launch_bounds__(256) void gemm_ks_t(
    const unsigned short* __restrict__ A, const void* __restrict__ Wp,
    const float* __restrict__ bias, const double* __restrict__ ssum, double cnt,
    float* __restrict__ p0, float* __restrict__ pext,
    int M, int N, int K, int Klen)
{
  __shared__ unsigned short As[128][40];
  __shared__ unsigned short Bs[128][40];
  int tid = threadIdx.x;
  int wave = tid >> 6, lane = tid & 63;
  int wm = wave >> 1, wn = wave & 1;
  int bm = blockIdx.y, bn = blockIdx.x, z = blockIdx.z;

  float s = 1.f, T = 0.f;
  if (ssum){
    double s64 = ssum[0] / cnt + 1e-8;
    s = (float)s64;
    T = tern_thresh(s64);
  }

  int arow = tid >> 1, achunk = tid & 1;
  int kbase = z * Klen;
  const unsigned short* Ag = A + (size_t)(bm * 128 + arow) * K + kbase + achunk * 16;
  const float* Wg32 = (const float*)Wp + (size_t)(bn * 128 + arow) * K + kbase + achunk * 16;
  const unsigned short* Wg16 = (const unsigned short*)Wp + (size_t)(bn * 128 + arow) * K + kbase + achunk * 16;

  floatx4 acc[4][4];
  #pragma unroll
  for (int i = 0; i < 4; i++)
    #pragma unroll
    for (int j = 0; j < 4; j++)
      acc[i][j] = (floatx4){0.f, 0.f, 0.f, 0.f};

  for (int k0 = 0; k0 < Klen; k0 += 32){
    __syncthreads();
    uint4 a0 = *(const uint4*)(Ag + k0);
    uint4 a1 = *(const uint4*)(Ag + k0 + 8);
    *(uint4*)&As[arow][achunk * 16]     = a0;
    *(uint4*)&As[arow][achunk * 16 + 8] = a1;
    if (WM == 2){
      uint4 b0 = *(const uint4*)(Wg16 + k0);
      uint4 b1 = *(const uint4*)(Wg16 + k0 + 8);
      *(uint4*)&Bs[arow][achunk * 16]     = b0;
      *(uint4*)&Bs[arow][achunk * 16 + 8] = b1;
    } else {
      unsigned short tmp[16];
      #pragma unroll
      for (int q = 0; q < 4; q++){
        float4 wv = *(const float4*)(Wg32 + k0 + q * 4);
        tmp[q*4+0] = (wv.x > T) ? 0x3F80 : ((wv.x < -T) ? 0xBF80 : 0);
        tmp[q*4+1] = (wv.y > T) ? 0x3F80 : ((wv.y < -T) ? 0xBF80 : 0);
        tmp[q*4+2] = (wv.z > T) ? 0x3F80 : ((wv.z < -T) ? 0xBF80 : 0);
        tmp[q*4+3] = (wv.w > T) ? 0x3F80 : ((wv.w < -T) ? 0xBF80 : 0);
      }
      *(uint4*)&Bs[arow][achunk * 16]     = *(uint4*)&tmp[0];
      *(uint4*)&Bs[arow][achunk * 16 + 8] = *(uint4*)&tmp[8];
    }
    __syncthreads();

    int kq = lane >> 4, mr = lane & 15;
    short8 af[4], bf[4];
    #pragma unroll
    for (int i = 0; i < 4; i++) af[i] = *(const short8*)&As[wm*64 + i*16 + mr][kq*8];
    #pragma unroll
    for (int j = 0; j < 4; j++) bf[j] = *(const short8*)&Bs[wn*64 + j*16 + mr][kq*8];
    #pragma unroll
    for (int i = 0; i < 4; i++)
      #pragma unroll
      for (int j = 0; j < 4; j++)
        acc[i][j] = __builtin_amdgcn_mfma_f32_16x16x32_bf16(af[i], bf[j], acc[i][j], 0, 0, 0);
  }

  float* outp = (z == 0) ? p0 : pext + (size_t)(z - 1) * M * N;
  int cr = lane >> 4, cc = lane & 15;
  #pragma unroll
  for (int j = 0; j < 4; j++){
    int col = bn * 128 + wn * 64 + j * 16 + cc;
    float bv = (z == 0 && bias) ? bias[col] : 0.f;
    #pragma unroll
    for (int i = 0; i < 4; i++){
      #pragma unroll
      for (int r = 0; r < 4; r++){
        int row = bm * 128 + wm * 64 + i * 16 + cr * 4 + r;
        outp[(size_t)row * N + col] = acc[i][j][r] * s + bv;
      }
    }
  }
}

// ---------------- bf16 MFMA GEMM (256x128 tile, 512 threads) ----------------
template<int WM>
__global__ __launch_bounds__(512) void gemm256_t(
    const unsigned short* __restrict__ A, const void* __restrict__ Wp,
    const float* __restrict__ bias, const double* __restrict__ ssum, double cnt,
    int relu, float* __restrict__ outf, unsigned short* __restrict__ outb,
    int M, int N, int K)
{
  __shared__ unsigned short As[256][40];
  __shared__ unsigned short Bs[128][40];
  int tid = threadIdx.x;
  int wave = tid >> 6, lane = tid & 63;
  int wm = wave >> 1, wn = wave & 1;   // wm 0..3, wn 0..1
  int bm = blockIdx.y, bn = blockIdx.x;

  float s = 1.f, T = 0.f;
  if (ssum){
    double s64 = ssum[0] / cnt + 1e-8;
    s = (float)s64;
    T = tern_thresh(s64);
  }

  int arow = tid >> 1, achunk = tid & 1;          // 256 rows x 2 chunks of 16
  int wrow = tid >> 2, wchunk = tid & 3;          // 128 rows x 4 chunks of 8
  const unsigned short* Ag = A + (size_t)(bm * 256 + arow) * K + achunk * 16;
  const float* Wg32 = (const float*)Wp + (size_t)(bn * 128 + wrow) * K + wchunk * 8;
  const unsigned short* Wg16 = (const unsigned short*)Wp + (size_t)(bn * 128 + wrow) * K + wchunk * 8;

  floatx4 acc[4][4];
  #pragma unroll
  for (int i = 0; i < 4; i++)
    #pragma unroll
    for (int j = 0; j < 4; j++)
      acc[i][j] = (floatx4){0.f, 0.f, 0.f, 0.f};

  for (int k0 = 0; k0 < K; k0 += 32){
    __syncthreads();
    uint4 a0 = *(const uint4*)(Ag + k0);
    uint4 a1 = *(const uint4*)(Ag + k0 + 8);
    *(uint4*)&As[arow][achunk * 16]     = a0;
    *(uint4*)&As[arow][achunk * 16 + 8] = a1;
    if (WM == 2){
      uint4 b0 = *(const uint4*)(Wg16 + k0);
      *(uint4*)&Bs[wrow][wchunk * 8] = b0;
    } else {
      unsigned short tmp[8];
      float4 w0 = *(const float4*)(Wg32 + k0);
      float4 w1 = *(const float4*)(Wg32 + k0 + 4);
      if (WM == 1){
        tmp[0] = (w0.x > T) ? 0x3F80 : ((w0.x < -T) ? 0xBF80 : 0);
        tmp[1] = (w0.y > T) ? 0x3F80 : ((w0.y < -T) ? 0xBF80 : 0);
        tmp[2] = (w0.z > T) ? 0x3F80 : ((w0.z < -T) ? 0xBF80 : 0);
        tmp[3] = (w0.w > T) ? 0x3F80 : ((w0.w < -T) ? 0xBF80 : 0);
        tmp[4] = (w1.x > T) ? 0x3F80 : ((w1.x < -T) ? 0xBF80 : 0);
        tmp[5] = (w1.y > T) ? 0x3F80 : ((w1.y < -T) ? 0xBF80 : 0);
        tmp[6] = (w1.z > T) ? 0x3F80 : ((w1.z < -T) ? 0xBF80 : 0);
        tmp[7] = (w1.w > T) ? 0x3F80 : ((w1.w < -T) ? 0xBF80 : 0);
      } else {
        tmp[0] = f2b(w0.x); tmp[1] = f2b(w0.y); tmp[2] = f2b(w0.z); tmp[3] = f2b(w0.w);
        tmp[4] = f2b(w1.x); tmp[5] = f2b(w1.y); tmp[6] = f2b(w1.z); tmp[7] = f2b(w1.w);
      }
      *(uint2*)&Bs[wrow][wchunk * 8]     = *(uint2*)&tmp[0];
      *(uint2*)&Bs[wrow][wchunk * 8 + 4] = *(uint2*)&tmp[4];
    }
    __syncthreads();

    int kq = lane >> 4, mr = lane & 15;
    short8 af[4], bf[4];
    #pragma unroll
    for (int i = 0; i < 4; i++) af[i] = *(const short8*)&As[wm*64 + i*16 + mr][kq*8];
    #pragma unroll
    for (int j = 0; j < 4; j++) bf[j] = *(const short8*)&Bs[wn*64 + j*16 + mr][kq*8];
    #pragma unroll
    for (int i = 0; i < 4; i++)
      #pragma unroll
      for (int j = 0; j < 4; j++)
        acc[i][j] = __builtin_amdgcn_mfma_f32_16x16x32_bf16(af[i], bf[j], acc[i][j], 0, 0, 0);
  }

  int cr = lane >> 4, cc = lane & 15;
  #pragma unroll
  for (int j = 0; j < 4; j++){
    int col = bn * 128 + wn * 64 + j * 16 + cc;
    float bv = bias ? bias[col] : 0.f;
    #pragma unroll
    for (int i = 0; i < 4; i++){
      #pragma unroll
      for (int r = 0; r < 4; r++){
        int row = bm * 256 + wm * 64 + i * 16 + cr * 4 + r;
        float v = acc[i][j][r] * s + bv;
        if (relu) v = fmaxf(v, 0.f);
        size_t idx = (size_t)row * N + col;
        if (outf) outf[idx] = v;
        if (outb) outb[idx] = f2b(v);
      }
    }
  }
}

// ---------------- prep pointers for in-GRU weave ----------------
struct PrepPtrs { const float* src[9]; unsigned short* dst[9]; };

// ---------------- persistent GRU with step-woven weight prep ----------------
// Round-12 configuration restored (sleep(8) regression reverted; the +48us
// matched the added detection granularity exactly -> poll load immaterial,
// granularity on critical path). Hybrid poll: first 8 spins busy (pure-RTT
// detection for near-ready data), then s_sleep(1) (half round-12's quantum;
// round-13 evidence says the extra request load is harmless).
// All arithmetic/protocol unchanged from round 12 (bit-exact h).
template<bool PREP>
__global__ __launch_bounds__(512) void gru_prep_kernel(
    const float* __restrict__ gi, const float* __restrict__ whh, const float* __restrict__ bhh,
    unsigned long long* __restrict__ hbuf,
    float* __restrict__ hs, unsigned short* __restrict__ hsb,
    PrepPtrs pp, double* __restrict__ parts, double* __restrict__ scales)
{
  __shared__ __align__(16) float lds_h[2][Dm];
  __shared__ float lds_gh[24];
  __shared__ double lds_aux[16];
  int w = blockIdx.x, tid = threadIdx.x;
  int bb = w & 1, slice = w >> 1;     // slice in [0,128)
  int d0 = slice * 8;
  int o = tid >> 4, c = tid & 15;     // dot o (24 dots), k-chunk c
  bool active = (o < 24);
  int g = o >> 3, dl = o & 7;         // gate, local dim
  int wrow = g * Dm + d0 + dl;
  float4 wr0 = {0,0,0,0}, wr1 = wr0, wr2 = wr0, wr3 = wr0,
         wr4 = wr0, wr5 = wr0, wr6 = wr0, wr7 = wr0,
         wr8 = wr0, wr9 = wr0, wr10 = wr0, wr11 = wr0,
         wr12 = wr0, wr13 = wr0, wr14 = wr0, wr15 = wr0;
  if (active){
    const float* wsrc = whh + (size_t)wrow * Dm + c * 4;
    wr0  = *(const float4*)(wsrc +  0*64);  wr1  = *(const float4*)(wsrc +  1*64);
    wr2  = *(const float4*)(wsrc +  2*64);  wr3  = *(const float4*)(wsrc +  3*64);
    wr4  = *(const float4*)(wsrc +  4*64);  wr5  = *(const float4*)(wsrc +  5*64);
    wr6  = *(const float4*)(wsrc +  6*64);  wr7  = *(const float4*)(wsrc +  7*64);
    wr8  = *(const float4*)(wsrc +  8*64);  wr9  = *(const float4*)(wsrc +  9*64);
    wr10 = *(const float4*)(wsrc + 10*64);  wr11 = *(const float4*)(wsrc + 11*64);
    wr12 = *(const float4*)(wsrc + 12*64);  wr13 = *(const float4*)(wsrc + 13*64);
    wr14 = *(const float4*)(wsrc + 14*64);  wr15 = *(const float4*)(wsrc + 15*64);
  }
  float bhval = (active && c == 0) ? bhh[wrow] : 0.f;

  int gidx = tid * 2;                 // this thread's 2 packed entries (own batch)
  bool self = ((tid >> 2) == slice);  // own window [8*slice, 8*slice+8)
  int dd = tid;                       // only meaningful for tid<8
  int dth = d0 + (tid & 7);
  float pir = 0.f, piz = 0.f, pin = 0.f;
  if (tid < 8){
    const float* girow = gi + (size_t)bb * Sm * (3 * Dm);
    pir = girow[dth]; piz = girow[Dm + dth]; pin = girow[2*Dm + dth];
  }

  // ---- prep state ----
  int myslot = 0, iters = 0, nthr = 0;
  const float4* psrc = nullptr;
  ushort4* pdst = nullptr;
  double acc = 0.0, fin = 0.0;
  float4 pend = {0.f, 0.f, 0.f, 0.f};
  float Tq = 0.f;
  int pbase = 0, npar = 0;
  double mycnt = 1.0;
  if (PREP){
    int rank;
    if (w < 128){ myslot = w >> 4; rank = ((w & 15) << 9) | tid; nthr = 8192;  iters = 128; }
    else        { myslot = 8;      rank = ((w - 128) << 9) | tid; nthr = 65536; iters = 125; }
    psrc = (const float4*)pp.src[myslot] + rank;
    pdst = (ushort4*)pp.dst[myslot] + rank;
    pbase = (w < 8) ? w * 16 : 128;
    npar  = (w < 8) ? 16 : 128;
    mycnt = (myslot == 8) ? (double)Vm * (double)Dm : (double)Nm * (double)Dm;
    pend = psrc[0];                   // prefetch absum element 0
  }

  for (int t = 0; t < Sm; t++){
    if (PREP){
      if (t < iters){
        acc += (double)fabsf(pend.x) + (double)fabsf(pend.y)
             + (double)fabsf(pend.z) + (double)fabsf(pend.w);
        if (t + 1 < iters) pend = psrc[(size_t)(t + 1) * nthr];
      } else if (t == 132){
        double r = acc;
        #pragma unroll
        for (int off = 32; off; off >>= 1) r += __shfl_down(r, off, 64);
        if ((tid & 63) == 0) lds_aux[tid >> 6] = r;
        __syncthreads();              // t-uniform -> safe
        if (tid == 0){
          double tot = 0.0;
          #pragma unroll
          for (int i = 0; i < 8; i++) tot += lds_aux[i];
          __hip_atomic_store(&parts[w], tot, __ATOMIC_RELAXED, __HIP_MEMORY_SCOPE_AGENT);
        }
      } else if (t >= 140 && t < 268){
        if (w <= 8 && tid == 0 && (t - 140) < npar)
          fin += __hip_atomic_load(&parts[pbase + (t - 140)],
                                   __ATOMIC_RELAXED, __HIP_MEMORY_SCOPE_AGENT);
      } else if (t == 272){
        if (w <= 8 && tid == 0)
          __hip_atomic_store(&scales[1 + w], fin, __ATOMIC_RELAXED, __HIP_MEMORY_SCOPE_AGENT);
      } else if (t == 280){
        if (tid == 0)
          lds_aux[9] = __hip_atomic_load(&scales[1 + myslot],
                                         __ATOMIC_RELAXED, __HIP_MEMORY_SCOPE_AGENT);
      } else if (t == 284){
        double s64 = lds_aux[9] / mycnt + 1e-8;   // lds_aux[9] sync'd by step barriers
        Tq = tern_thresh(s64);
        pend = psrc[0];               // prefetch pack element 0
      } else if (t >= 288 && t < 288 + iters){
        int k = t - 288;
        ushort4 u;
        u.x = (pend.x > Tq) ? 0x3F80 : ((pend.x < -Tq) ? 0xBF80 : 0);
        u.y = (pend.y > Tq) ? 0x3F80 : ((pend.y < -Tq) ? 0xBF80 : 0);
        u.z = (pend.z > Tq) ? 0x3F80 : ((pend.z < -Tq) ? 0xBF80 : 0);
        u.w = (pend.w > Tq) ? 0x3F80 : ((pend.w < -Tq) ? 0xBF80 : 0);
        pdst[(size_t)k * nthr] = u;
        if (k + 1 < iters) pend = psrc[(size_t)(k + 1) * nthr];
      }
    }

    float* lh = lds_h[t & 1];
    if (!self || t == 0){
      const unsigned long long* hsrc = hbuf + (size_t)(t & 1) * 2048 + bb * 1024 + gidx;
      const unsigned long long* xsrc = hbuf + (size_t)(t & 1) * 2048 + (1 - bb) * 1024;
      unsigned long long e0, e1;
      int spins = 0;
      for (;;){
        e0 = __hip_atomic_load(hsrc + 0, __ATOMIC_RELAXED, __HIP_MEMORY_SCOPE_AGENT);
        e1 = __hip_atomic_load(hsrc + 1, __ATOMIC_RELAXED, __HIP_MEMORY_SCOPE_AGENT);
        bool ok = ((unsigned)(e0 >> 32) == (unsigned)t) &&
                  ((unsigned)(e1 >> 32) == (unsigned)t);
        if (PREP && tid == 256){      // cross-batch coupling (provable lockstep)
          unsigned long long ex =
              __hip_atomic_load(xsrc, __ATOMIC_RELAXED, __HIP_MEMORY_SCOPE_AGENT);
          ok = ok && ((unsigned)(ex >> 32) == (unsigned)t);
        }
        if (ok) break;
        ++spins;
        if (spins > 8) __builtin_amdgcn_s_sleep(1);
        if (spins > (1 << 17)) break;   // safety: degrade, don't hang
      }
      lh[gidx + 0] = __uint_as_float((unsigned)e0);
      lh[gidx + 1] = __uint_as_float((unsigned)e1);
    }
    __syncthreads();   // sync A: lds_h[t&1] complete
    float dacc = 0.f;
    if (active){
      const float* hb = lh + c * 4;
      float4 hv;
      #define GDOT(J, W) hv = *(const float4*)(hb + (J)*64); \
          dacc += W.x*hv.x + W.y*hv.y + W.z*hv.z + W.w*hv.w;
      GDOT(0,wr0)  GDOT(1,wr1)  GDOT(2,wr2)  GDOT(3,wr3)
      GDOT(4,wr4)  GDOT(5,wr5)  GDOT(6,wr6)  GDOT(7,wr7)
      GDOT(8,wr8)  GDOT(9,wr9)  GDOT(10,wr10) GDOT(11,wr11)
      GDOT(12,wr12) GDOT(13,wr13) GDOT(14,wr14) GDOT(15,wr15)
      #undef GDOT
    }
    #pragma unroll
    for (int off = 8; off; off >>= 1) dacc += __shfl_xor(dacc, off, 16);
    if (active && c == 0) lds_gh[o] = dacc + bhval;
    __syncthreads();   // sync B: gates ready
    if (tid < 8){
      float gr = lds_gh[dd];
      float gz = lds_gh[8 + dd];
      float gn = lds_gh[16 + dd];
      float hv = lh[dth];
      float rr = 1.f / (1.f + expf(-(pir + gr)));
      float zz = 1.f / (1.f + expf(-(piz + gz)));
      float nn = tanhf(pin + rr * gn);
      float hnew = (1.f - zz) * nn + zz * hv;
      unsigned long long pack =
          ((unsigned long long)(unsigned)(t + 1) << 32) | (unsigned long long)__float_as_uint(hnew);
      __hip_atomic_store(hbuf + (size_t)((t + 1) & 1) * 2048 + bb * 1024 + dth, pack,
                         __ATOMIC_RELAXED, __HIP_MEMORY_SCOPE_AGENT);
      lds_h[(t + 1) & 1][dth] = hnew;
      if (t + 1 < Sm){
        const float* girow = gi + ((size_t)bb * Sm + (t+1)) * (3 * Dm);
        pir = girow[dth]; piz = girow[Dm + dth]; pin = girow[2*Dm + dth];
      }
      size_t oi = ((size_t)bb * Sm + t) * Dm + dth;
      hs[oi]  = hnew;
      hsb[oi] = f2b(hnew);
    }
  }
}

// ---------------- layernorm (+residual + up to 4 split-K partials) ----------------
__global__ __launch_bounds__(256) void ln_kernel(
    float* __restrict__ resid, const float* __restrict__ p0,
    const float* __restrict__ pext,
    const float* __restrict__ g, const float* __restrict__ b,
    float* __restrict__ outf, unsigned short* __restrict__ outb)
{
  int row = blockIdx.x;
  int d = threadIdx.x * 4;
  size_t base = (size_t)row * Dm + d;
  float4 v = *(float4*)(resid + base);
  if (p0){
    float4 a = *(const float4*)(p0 + base);
    v.x += a.x; v.y += a.y; v.z += a.z; v.w += a.w;
  }
  if (pext){
    const size_t stride = (size_t)1024 * Dm;
    #pragma unroll
    for (int e = 0; e < 3; e++){
      float4 a = *(const float4*)(pext + e * stride + base);
      v.x += a.x; v.y += a.y; v.z += a.z; v.w += a.w;
    }
  }
  float sum = v.x + v.y + v.z + v.w;
  float sq  = v.x*v.x + v.y*v.y + v.z*v.z + v.w*v.w;
  #pragma unroll
  for (int off = 32; off; off >>= 1){
    sum += __shfl_down(sum, off, 64);
    sq  += __shfl_down(sq,  off, 64);
  }
  __shared__ float red[4][2];
  __shared__ float bc[2];
  int lane = threadIdx.x & 63, wv = threadIdx.x >> 6;
  if (lane == 0){ red[wv][0] = sum; red[wv][1] = sq; }
  __syncthreads();
  if (threadIdx.x == 0){
    float st = red[0][0] + red[1][0] + red[2][0] + red[3][0];
    float qt = red[0][1] + red[1][1] + red[2][1] + red[3][1];
    float mu = st * (1.f / Dm);
    float var = qt * (1.f / Dm) - mu * mu;
    bc[0] = mu; bc[1] = rsqrtf(var + 1e-5f);
  }
  __syncthreads();
  float mu = bc[0], rs = bc[1];
  float4 gv = *(const float4*)(g + d);
  float4 bv = *(const float4*)(b + d);
  float4 y;
  y.x = (v.x - mu) * rs * gv.x + bv.x;
  y.y = (v.y - mu) * rs * gv.y + bv.y;
  y.z = (v.z - mu) * rs * gv.z + bv.z;
  y.w = (v.w - mu) * rs * gv.w + bv.w;
  if (outf) *(float4*)(outf + base) = y;
  if (outb){
    ushort4 u = make_ushort4(f2b(y.x), f2b(y.y), f2b(y.z), f2b(y.w));
    *(ushort4*)(outb + base) = u;
  }
}

extern "C" void kernel_launch(void* const* d_in, const int* in_sizes, int n_in,
                              void* d_out, int out_size, void* d_ws, size_t ws_size,
                              hipStream_t stream)
{
  const int*   ids    = (const int*)  d_in[0];
  const float* emb    = (const float*)d_in[1];
  const float* pos    = (const float*)d_in[2];
  const float* wih    = (const float*)d_in[3];
  const float* whh    = (const float*)d_in[4];
  const float* bih    = (const float*)d_in[5];
  const float* bhh    = (const float*)d_in[6];
  const float* syn_w  = (const float*)d_in[7];
  const float* syn_b  = (const float*)d_in[8];
  const float* out_w  = (const float*)d_in[9];
  const float* out_b  = (const float*)d_in[10];
  const float* ln_g   = (const float*)d_in[11];
  const float* ln_b   = (const float*)d_in[12];
  const float* on_g   = (const float*)d_in[13];
  const float* on_b   = (const float*)d_in[14];
  const float* head_w = (const float*)d_in[15];
  const float* head_b = (const float*)d_in[16];
  float* logits = (float*)d_out;

  char* ws = (char*)d_ws;
  double*             scales = (double*)ws;                         // 10 doubles
  unsigned long long* hbuf   = (unsigned long long*)(ws + 4096);    // 2*2048 packed {tag,h} (32KB)
  double*             parts  = (double*)(ws + 36864);               // 512 doubles used (4KB of 40KB)
  unsigned short*     xb     = (unsigned short*)(ws + 131072);      // [1024,1024] bf16 (2MB)
  float*              hs     = (float*)(ws + ((size_t)4  << 20));   // [1024,1024] f32  (4MB)
  unsigned short*     hidden = (unsigned short*)(ws + ((size_t)12 << 20)); // [1024,4096] bf16 (8MB)
  float*              outbuf = (float*)(ws + ((size_t)20 << 20));   // [1024,1024] f32  (4MB)
  float*              gi     = (float*)(ws + ((size_t)24 << 20));   // [1024,3072] f32  (12MB; split-K partials after GRU)
  // packed bf16 weights (guarded by ws_size)
  unsigned short*     wih_b  = (unsigned short*)(ws + ((size_t)36 << 20));  // 6MB
  unsigned short*     syn_bk = (unsigned short*)(ws + ((size_t)42 << 20));  // 32MB
  unsigned short*     out_bk = (unsigned short*)(ws + ((size_t)74 << 20));  // 32MB
  unsigned short*     head_bk= (unsigned short*)(ws + ((size_t)106 << 20)); // 62.5MB
  const size_t NEED = ((size_t)106 << 20) + (size_t)Vm * Dm * 2;
  const bool packed = (ws_size >= NEED);

  // zero scales + hbuf + parts head (tags=0 == initial h state for t=0)
  hipMemsetAsync(d_ws, 0, 36864, stream);

  const double cnt_nd = (double)Nm * (double)Dm;
  const double cnt_vd = (double)Vm * (double)Dm;

  if (packed){
    // pre-GRU: only emb scale (for embed) + wih pack (for gi GEMM)
    AbsumArgs aa; aa.src[0] = emb; aa.n4[0] = (long)Vm * Dm / 4;
    absum_all_kernel<<<dim3(512, 1), 256, 0, stream>>>(aa, parts);
    absum_final_kernel<<<1, 256, 0, stream>>>(parts, scales);
    PackArgs pw;
    pw.src[0] = wih; pw.dst[0] = wih_b; pw.n4[0] = (long)(3*Dm)*Dm/4;
    pw.sidx[0] = -1; pw.cnt[0] = 1.0;
    pack_all_kernel<<<dim3(512, 1), 256, 0, stream>>>(pw, scales);
  } else {
    // fallback: full serial absum over all 10 slots (no packing)
    AbsumArgs aa;
    aa.src[0] = emb;    aa.n4[0] = (long)Vm * Dm / 4;
    for (int l = 0; l < Lm; l++){
      aa.src[1 + l] = syn_w + (size_t)l * Nm * Dm; aa.n4[1 + l] = (long)Nm * Dm / 4;
      aa.src[5 + l] = out_w + (size_t)l * Dm * Nm; aa.n4[5 + l] = (long)Nm * Dm / 4;
    }
    aa.src[9] = head_w; aa.n4[9] = (long)Vm * Dm / 4;
    absum_all_kernel<<<dim3(512, 10), 256, 0, stream>>>(aa, parts);
    absum_final_kernel<<<10, 256, 0, stream>>>(parts, scales);
  }

  // x = tern(emb)[ids] + pos  (bf16)
  embed_kernel<<<1024, 256, 0, stream>>>(ids, emb, pos, scales, xb);

  // gi = x @ wih^T + bih
  if (packed)
    gemm_t<2><<<dim3(3072/128, 1024/128), 256, 0, stream>>>(
        xb, wih_b, bih, nullptr, 0.0, 0, gi, nullptr, 1024, 3072, 1024);
  else
    gemm_t<0><<<dim3(3072/128, 1024/128), 256, 0, stream>>>(
        xb, wih, bih, nullptr, 0.0, 0, gi, nullptr, 1024, 3072, 1024);

  // sequential GRU with step-woven syn/out/head scale+pack
  {
    PrepPtrs pp;
    for (int l = 0; l < Lm; l++){
      pp.src[l]     = syn_w + (size_t)l * Nm * Dm; pp.dst[l]     = syn_bk + (size_t)l * Nm * Dm;
      pp.src[4 + l] = out_w + (size_t)l * Dm * Nm; pp.dst[4 + l] = out_bk + (size_t)l * Dm * Nm;
    }
    pp.src[8] = head_w; pp.dst[8] = head_bk;
    if (packed)
      gru_prep_kernel<true><<<256, 512, 0, stream>>>(gi, whh, bhh, hbuf, hs, xb,
                                                     pp, parts, scales);
    else
      gru_prep_kernel<false><<<256, 512, 0, stream>>>(gi, whh, bhh, hbuf, hs, xb,
                                                      pp, parts, scales);
  }

  for (int l = 0; l < Lm; l++){
    // hidden = relu(x @ tern(syn_w)^T + syn_b)  (bf16)
    if (packed)
      gemm_t<2><<<dim3(4096/128, 1024/128), 256, 0, stream>>>(
          xb, syn_bk + (size_t)l * Nm * Dm, syn_b + (size_t)l * Nm,
          scales + 1 + l, cnt_nd, 1, nullptr, hidden, 1024, 4096, 1024);
    else
      gemm_t<1><<<dim3(4096/128, 1024/128), 256, 0, stream>>>(
          xb, syn_w + (size_t)l * Nm * Dm, syn_b + (size_t)l * Nm,
          scales + 1 + l, cnt_nd, 1, nullptr, hidden, 1024, 4096, 1024);
    // out partials = hidden @ tern(out_w)^T (split-K=4)
    if (packed)
      gemm_ks_t<2><<<dim3(1024/128, 1024/128, 4), 256, 0, stream>>>(
          hidden, out_bk + (size_t)l * Dm * Nm, out_b + (size_t)l * Dm,
          scales + 5 + l, cnt_nd, outbuf, gi, 1024, 1024, 4096, 1024);
    else
      gemm_ks_t<1><<<dim3(1024/128, 1024/128, 4), 256, 0, stream>>>(
          hidden, out_w + (size_t)l * Dm * Nm, out_b + (size_t)l * Dm,
          scales + 5 + l, cnt_nd, outbuf, gi, 1024, 1024, 4096, 1024);
    // x = LN(resid + sum of partials)  -> hs (f32) and xb (bf16)
    ln_kernel<<<1024, 256, 0, stream>>>(hs, outbuf, gi,
        ln_g + (size_t)l * Dm, ln_b + (size_t)l * Dm, hs, xb);
  }
  // final LN -> xb (bf16)
  ln_kernel<<<1024, 256, 0, stream>>>(hs, nullptr, nullptr, on_g, on_b, nullptr, xb);

  // logits = x @ tern(head_w)^T + head_b  (f32 -> d_out), 256-row tiles
  if (packed)
    gemm256_t<2><<<dim3(32000/128, 1024/256), 512, 0, stream>>>(
        xb, head_bk, head_b, scales + 9, cnt_vd, 0, logits, nullptr, 1024, 32000, 1024);
  else
    gemm256_t<1><<<dim3(32000/128, 1024/256), 512, 0, stream>>>(
        xb, head_w, head_b, scales + 9, cnt_vd, 0, logits, nullptr, 1024, 32000, 1024);
}